// Round 1
// baseline (492.787 us; speedup 1.0000x reference)
//
#include <hip/hip_runtime.h>
#include <hip/hip_bf16.h>

#define TPB 256

// ---------------- graph construction ----------------

__global__ void count_deg(const int* __restrict__ ei, int* __restrict__ cnt, int E) {
    int e = blockIdx.x * blockDim.x + threadIdx.x;
    if (e < E) atomicAdd(&cnt[ei[E + e]], 1);
}

// per-256-block exclusive scan of cnt -> rowptr (staged), block sums -> bsum,
// also dis[i] = rsqrt(1 + cnt[i])  (self-loop included analytically)
__global__ void scan_a(const int* __restrict__ cnt, int* __restrict__ rowptr,
                       float* __restrict__ dis, int* __restrict__ bsum, int N) {
    __shared__ int sd[TPB];
    int t = threadIdx.x;
    int i = blockIdx.x * TPB + t;
    int v = (i < N) ? cnt[i] : 0;
    if (i < N) dis[i] = rsqrtf((float)(v + 1));
    sd[t] = v;
    __syncthreads();
    for (int off = 1; off < TPB; off <<= 1) {
        int x = 0;
        if (t >= off) x = sd[t - off];
        __syncthreads();
        sd[t] += x;
        __syncthreads();
    }
    if (i < N) rowptr[i] = sd[t] - v;               // exclusive
    if (t == TPB - 1) bsum[blockIdx.x] = sd[t];     // inclusive total
}

__global__ void scan_b(int* __restrict__ bsum, int nb) {
    __shared__ int sd[TPB];
    int t = threadIdx.x;
    int v = (t < nb) ? bsum[t] : 0;
    sd[t] = v;
    __syncthreads();
    for (int off = 1; off < TPB; off <<= 1) {
        int x = 0;
        if (t >= off) x = sd[t - off];
        __syncthreads();
        sd[t] += x;
        __syncthreads();
    }
    if (t < nb) bsum[t] = sd[t] - v;                // exclusive block offsets
}

__global__ void scan_c(int* __restrict__ rowptr, const int* __restrict__ bsum,
                       int N, int E) {
    int i = blockIdx.x * TPB + threadIdx.x;
    if (i < N) rowptr[i] += bsum[blockIdx.x];
    if (i == 0) rowptr[N] = E;
}

__global__ void fill_csr(const int* __restrict__ ei, const int* __restrict__ rowptr,
                         int* __restrict__ cursor, int* __restrict__ col, int E) {
    int e = blockIdx.x * blockDim.x + threadIdx.x;
    if (e >= E) return;
    int s = ei[e], d = ei[E + e];
    int pos = rowptr[d] + atomicAdd(&cursor[d], 1);
    col[pos] = s;
}

// ---------------- transpose 128x128 weights (for coalesced B staging in feat2) ----

__global__ void transpose_w(const float* __restrict__ Wa, float* __restrict__ Wta,
                            const float* __restrict__ Wb, float* __restrict__ Wtb) {
    __shared__ float tile[32][33];
    const float* W = (blockIdx.y == 0) ? Wa : Wb;
    float* Wt      = (blockIdx.y == 0) ? Wta : Wtb;
    int bx = blockIdx.x & 3, by = blockIdx.x >> 2;
    int tx = threadIdx.x & 31, ty = threadIdx.x >> 5;   // 256 thr: ty 0..7
    for (int r = ty; r < 32; r += 8)
        tile[r][tx] = W[(by * 32 + r) * 128 + bx * 32 + tx];
    __syncthreads();
    for (int r = ty; r < 32; r += 8)
        Wt[(bx * 32 + r) * 128 + by * 32 + tx] = tile[tx][r];
}

// ---------------- layer 1: t[i, 0:128]=dis*x@Wc1^T, t[i,128:256]=dis*x@Wv1^T ----

__global__ void feat1(const float* __restrict__ x, const float* __restrict__ Wc,
                      const float* __restrict__ Wv, const float* __restrict__ dis,
                      float* __restrict__ out, int N) {
    __shared__ float xt[16][16];
    int t = threadIdx.x;
    int n0 = blockIdx.x * 16;
    {
        int n = t >> 4, k = t & 15;
        int node = n0 + n;
        xt[n][k] = (node < N) ? x[node * 16 + k] : 0.f;
    }
    // each thread's 16-float weight row lives in registers (W is L1/L2-resident)
    const float* wrow = (t < 128) ? (Wc + t * 16) : (Wv + (t - 128) * 16);
    float4 w0 = *(const float4*)(wrow + 0);
    float4 w1 = *(const float4*)(wrow + 4);
    float4 w2 = *(const float4*)(wrow + 8);
    float4 w3 = *(const float4*)(wrow + 12);
    __syncthreads();
    for (int n = 0; n < 16; ++n) {
        int node = n0 + n;
        if (node >= N) break;
        const float* xr = xt[n];
        float s = w0.x * xr[0] + w0.y * xr[1] + w0.z * xr[2] + w0.w * xr[3]
                + w1.x * xr[4] + w1.y * xr[5] + w1.z * xr[6] + w1.w * xr[7]
                + w2.x * xr[8] + w2.y * xr[9] + w2.z * xr[10] + w2.w * xr[11]
                + w3.x * xr[12] + w3.y * xr[13] + w3.z * xr[14] + w3.w * xr[15];
        out[node * 256 + t] = dis[node] * s;
    }
}

// ---------------- aggregation: out[i] = relu(dis[i]*(self + sum_{s} t[s]) + b) ----
// one wave per node; lane l handles float4 at feature 4l (256 feats total)

__global__ void agg(const float4* __restrict__ tin, const int* __restrict__ rowptr,
                    const int* __restrict__ col, const float* __restrict__ dis,
                    const float* __restrict__ bc, const float* __restrict__ bv,
                    float4* __restrict__ out, int N) {
    int wid = blockIdx.x * (blockDim.x >> 6) + (threadIdx.x >> 6);
    if (wid >= N) return;
    int lane = threadIdx.x & 63;
    float4 acc = tin[wid * 64 + lane];      // self term (t is dis-prescaled)
    int e = rowptr[wid], end = rowptr[wid + 1];
    for (; e + 1 < end; e += 2) {
        int s0 = col[e], s1 = col[e + 1];
        float4 m0 = tin[s0 * 64 + lane];
        float4 m1 = tin[s1 * 64 + lane];
        acc.x += m0.x + m1.x; acc.y += m0.y + m1.y;
        acc.z += m0.z + m1.z; acc.w += m0.w + m1.w;
    }
    if (e < end) {
        int s0 = col[e];
        float4 m0 = tin[s0 * 64 + lane];
        acc.x += m0.x; acc.y += m0.y; acc.z += m0.z; acc.w += m0.w;
    }
    float d = dis[wid];
    int f = lane * 4;
    float4 b = (f < 128) ? *(const float4*)(bc + f) : *(const float4*)(bv + f - 128);
    float4 r;
    r.x = fmaxf(fmaf(d, acc.x, b.x), 0.f);
    r.y = fmaxf(fmaf(d, acc.y, b.y), 0.f);
    r.z = fmaxf(fmaf(d, acc.z, b.z), 0.f);
    r.w = fmaxf(fmaf(d, acc.w, b.w), 0.f);
    out[wid * 64 + lane] = r;
}

// ---------------- layer 2 GEMM: t2 = dis * (h @ W^T), fused c|v halves ----------
// grid (ceil(N/64), 4): blockIdx.y: 0,1 -> policy (Wtc, h[:,0:128]); 2,3 -> value
// tile: 64 nodes x 64 feats, K=128 fully staged; thread = 4x4 micro-tile

__global__ void feat2(const float* __restrict__ h, const float* __restrict__ Wtc,
                      const float* __restrict__ Wtv, const float* __restrict__ dis,
                      float* __restrict__ out, int N) {
    __shared__ float As[64][132];   // [n][k], +4 pad
    __shared__ float Bs[128][64];   // [k][f]
    int tid = threadIdx.x;
    int n0 = blockIdx.x * 64;
    int fy = blockIdx.y;
    int koff = (fy >= 2) ? 128 : 0;
    const float* Wt = (fy >= 2) ? Wtv : Wtc;
    int fbase = (fy & 1) * 64;

    {   // stage A: coalesced 512B row segments
        int nr = tid >> 5;            // 0..7
        int k4 = (tid & 31) * 4;      // 0..124
        for (int p = 0; p < 8; ++p) {
            int n = p * 8 + nr;
            int node = n0 + n;
            float4 v = make_float4(0.f, 0.f, 0.f, 0.f);
            if (node < N) v = *(const float4*)(h + node * 256 + koff + k4);
            *(float4*)(&As[n][k4]) = v;
        }
    }
    {   // stage B from pre-transposed W: coalesced along f
        int kr = tid >> 4;            // 0..15
        int f4 = (tid & 15) * 4;
        for (int p = 0; p < 8; ++p) {
            int k = p * 16 + kr;
            float4 v = *(const float4*)(Wt + k * 128 + fbase + f4);
            *(float4*)(&Bs[k][f4]) = v;
        }
    }
    __syncthreads();

    int tf = (tid & 15) * 4;
    int tn = (tid >> 4) * 4;
    float acc[4][4] = {};
#pragma unroll 4
    for (int k = 0; k < 128; ++k) {
        float4 b = *(const float4*)(&Bs[k][tf]);
        float a0 = As[tn + 0][k], a1 = As[tn + 1][k];
        float a2 = As[tn + 2][k], a3 = As[tn + 3][k];
        acc[0][0] = fmaf(a0, b.x, acc[0][0]); acc[0][1] = fmaf(a0, b.y, acc[0][1]);
        acc[0][2] = fmaf(a0, b.z, acc[0][2]); acc[0][3] = fmaf(a0, b.w, acc[0][3]);
        acc[1][0] = fmaf(a1, b.x, acc[1][0]); acc[1][1] = fmaf(a1, b.y, acc[1][1]);
        acc[1][2] = fmaf(a1, b.z, acc[1][2]); acc[1][3] = fmaf(a1, b.w, acc[1][3]);
        acc[2][0] = fmaf(a2, b.x, acc[2][0]); acc[2][1] = fmaf(a2, b.y, acc[2][1]);
        acc[2][2] = fmaf(a2, b.z, acc[2][2]); acc[2][3] = fmaf(a2, b.w, acc[2][3]);
        acc[3][0] = fmaf(a3, b.x, acc[3][0]); acc[3][1] = fmaf(a3, b.y, acc[3][1]);
        acc[3][2] = fmaf(a3, b.z, acc[3][2]); acc[3][3] = fmaf(a3, b.w, acc[3][3]);
    }

    int fo = ((fy >= 2) ? 128 : 0) + fbase;
    for (int r = 0; r < 4; ++r) {
        int node = n0 + tn + r;
        if (node >= N) continue;
        float d = dis[node];
        float4 o = make_float4(d * acc[r][0], d * acc[r][1],
                               d * acc[r][2], d * acc[r][3]);
        *(float4*)(out + node * 256 + fo + tf) = o;
    }
}

// ---------------- final 1-wide projections: one wave per node --------------------

__global__ void proj(const float* __restrict__ h, const float* __restrict__ Wp,
                     const float* __restrict__ bp, const float* __restrict__ Wvh,
                     const float* __restrict__ bvh, float* __restrict__ outm,
                     float* __restrict__ outv, int N) {
    int wid = blockIdx.x * (blockDim.x >> 6) + (threadIdx.x >> 6);
    if (wid >= N) return;
    int lane = threadIdx.x & 63;
    const float* hr = h + (size_t)wid * 256;
    float sc = hr[lane] * Wp[lane] + hr[64 + lane] * Wp[64 + lane];
    float sv = hr[128 + lane] * Wvh[lane] + hr[192 + lane] * Wvh[64 + lane];
    for (int off = 32; off; off >>= 1) {
        sc += __shfl_down(sc, off, 64);
        sv += __shfl_down(sv, off, 64);
    }
    if (lane == 0) {
        outm[wid] = sc + bp[0];
        outv[wid] = sv + bvh[0];
    }
}

// ---------------- launch ---------------------------------------------------------

extern "C" void kernel_launch(void* const* d_in, const int* in_sizes, int n_in,
                              void* d_out, int out_size, void* d_ws, size_t ws_size,
                              hipStream_t stream) {
    const float* x   = (const float*)d_in[0];
    const int*   ei  = (const int*)  d_in[1];
    const float* Wc1 = (const float*)d_in[2];
    const float* bc1 = (const float*)d_in[3];
    const float* Wc2 = (const float*)d_in[4];
    const float* bc2 = (const float*)d_in[5];
    const float* Wp  = (const float*)d_in[6];
    const float* bp  = (const float*)d_in[7];
    const float* Wv1 = (const float*)d_in[8];
    const float* bv1 = (const float*)d_in[9];
    const float* Wv2 = (const float*)d_in[10];
    const float* bv2 = (const float*)d_in[11];
    const float* Wvh = (const float*)d_in[12];
    const float* bvh = (const float*)d_in[13];

    const int N = in_sizes[0] / 16;   // 50000
    const int E = in_sizes[1] / 2;    // 800000

    // workspace layout (~107 MB)
    size_t off = 0;
    auto alloc = [&](size_t bytes) -> void* {
        void* p = (char*)d_ws + off;
        off += (bytes + 255) & ~(size_t)255;
        return p;
    };
    int*   cnt    = (int*)alloc((size_t)2 * N * sizeof(int));
    int*   cursor = cnt + N;                         // contiguous with cnt (one memset)
    int*   rowptr = (int*)alloc((size_t)(N + 1) * sizeof(int));
    int*   bsum   = (int*)alloc(256 * sizeof(int));
    float* dis    = (float*)alloc((size_t)N * sizeof(float));
    int*   col    = (int*)alloc((size_t)E * sizeof(int));
    float* Wtc    = (float*)alloc(128 * 128 * sizeof(float));
    float* Wtv    = (float*)alloc(128 * 128 * sizeof(float));
    float* buf0   = (float*)alloc((size_t)N * 256 * sizeof(float));
    float* buf1   = (float*)alloc((size_t)N * 256 * sizeof(float));

    float* outm = (float*)d_out;
    float* outv = outm + N;

    const int nbE = (E + TPB - 1) / TPB;     // 3125
    const int nbN = (N + TPB - 1) / TPB;     // 196

    hipMemsetAsync(cnt, 0, (size_t)2 * N * sizeof(int), stream);
    count_deg<<<nbE, TPB, 0, stream>>>(ei, cnt, E);
    scan_a<<<nbN, TPB, 0, stream>>>(cnt, rowptr, dis, bsum, N);
    scan_b<<<1, TPB, 0, stream>>>(bsum, nbN);
    scan_c<<<nbN, TPB, 0, stream>>>(rowptr, bsum, N, E);
    fill_csr<<<nbE, TPB, 0, stream>>>(ei, rowptr, cursor, col, E);
    transpose_w<<<dim3(16, 2), TPB, 0, stream>>>(Wc2, Wtc, Wv2, Wtv);

    // layer 1 (both branches fused): x -> buf0 -> agg -> buf1
    feat1<<<(N + 15) / 16, TPB, 0, stream>>>(x, Wc1, Wv1, dis, buf0, N);
    agg<<<(N + 3) / 4, TPB, 0, stream>>>((const float4*)buf0, rowptr, col, dis,
                                         bc1, bv1, (float4*)buf1, N);
    // layer 2: buf1 -> buf0 -> agg -> buf1
    feat2<<<dim3((N + 63) / 64, 4), TPB, 0, stream>>>(buf1, Wtc, Wtv, dis, buf0, N);
    agg<<<(N + 3) / 4, TPB, 0, stream>>>((const float4*)buf0, rowptr, col, dis,
                                         bc2, bv2, (float4*)buf1, N);
    // heads
    proj<<<(N + 3) / 4, TPB, 0, stream>>>(buf1, Wp, bp, Wvh, bvh, outm, outv, N);
}

// Round 2
// 384.096 us; speedup vs baseline: 1.2830x; 1.2830x over previous
//
#include <hip/hip_runtime.h>
#include <hip/hip_bf16.h>
#include <hip/hip_fp16.h>

#define TPB 256

// ---------------- graph construction ----------------

__global__ void count_deg(const int* __restrict__ ei, int* __restrict__ cnt, int E) {
    int e = blockIdx.x * blockDim.x + threadIdx.x;
    if (e < E) atomicAdd(&cnt[ei[E + e]], 1);
}

__global__ void scan_a(const int* __restrict__ cnt, int* __restrict__ rowptr,
                       float* __restrict__ dis, int* __restrict__ bsum, int N) {
    __shared__ int sd[TPB];
    int t = threadIdx.x;
    int i = blockIdx.x * TPB + t;
    int v = (i < N) ? cnt[i] : 0;
    if (i < N) dis[i] = rsqrtf((float)(v + 1));
    sd[t] = v;
    __syncthreads();
    for (int off = 1; off < TPB; off <<= 1) {
        int x = 0;
        if (t >= off) x = sd[t - off];
        __syncthreads();
        sd[t] += x;
        __syncthreads();
    }
    if (i < N) rowptr[i] = sd[t] - v;               // exclusive
    if (t == TPB - 1) bsum[blockIdx.x] = sd[t];     // inclusive total
}

__global__ void scan_b(int* __restrict__ bsum, int nb) {
    __shared__ int sd[TPB];
    int t = threadIdx.x;
    int v = (t < nb) ? bsum[t] : 0;
    sd[t] = v;
    __syncthreads();
    for (int off = 1; off < TPB; off <<= 1) {
        int x = 0;
        if (t >= off) x = sd[t - off];
        __syncthreads();
        sd[t] += x;
        __syncthreads();
    }
    if (t < nb) bsum[t] = sd[t] - v;                // exclusive block offsets
}

__global__ void scan_c(int* __restrict__ rowptr, const int* __restrict__ bsum,
                       int N, int E) {
    int i = blockIdx.x * TPB + threadIdx.x;
    if (i < N) rowptr[i] += bsum[blockIdx.x];
    if (i == 0) rowptr[N] = E;
}

__global__ void fill_csr(const int* __restrict__ ei, const int* __restrict__ rowptr,
                         int* __restrict__ cursor, int* __restrict__ col, int E) {
    int e = blockIdx.x * blockDim.x + threadIdx.x;
    if (e >= E) return;
    int s = ei[e], d = ei[E + e];
    int pos = rowptr[d] + atomicAdd(&cursor[d], 1);
    col[pos] = s;
}

// ---------------- transpose 128x128 weights -> Wt[k][f] = W[f][k] ----------------

__global__ void transpose_w(const float* __restrict__ Wa, float* __restrict__ Wta,
                            const float* __restrict__ Wb, float* __restrict__ Wtb) {
    __shared__ float tile[32][33];
    const float* W = (blockIdx.y == 0) ? Wa : Wb;
    float* Wt      = (blockIdx.y == 0) ? Wta : Wtb;
    int bx = blockIdx.x & 3, by = blockIdx.x >> 2;
    int tx = threadIdx.x & 31, ty = threadIdx.x >> 5;
    for (int r = ty; r < 32; r += 8)
        tile[r][tx] = W[(by * 32 + r) * 128 + bx * 32 + tx];
    __syncthreads();
    for (int r = ty; r < 32; r += 8)
        Wt[(bx * 32 + r) * 128 + by * 32 + tx] = tile[tx][r];
}

// ---------------- fp16 helpers ---------------------------------------------------

__device__ __forceinline__ float4 h4_to_f4(uint2 m) {
    __half2 h0 = *reinterpret_cast<const __half2*>(&m.x);
    __half2 h1 = *reinterpret_cast<const __half2*>(&m.y);
    float2 f0 = __half22float2(h0);
    float2 f1 = __half22float2(h1);
    return make_float4(f0.x, f0.y, f1.x, f1.y);
}

__device__ __forceinline__ unsigned pack_h2(float a, float b) {
    __half2 h = __floats2half2_rn(a, b);
    return *reinterpret_cast<unsigned*>(&h);
}

// ---------------- layer 1: t[i,0:128]=dis*x@Wc1^T, t[i,128:256]=dis*x@Wv1^T (fp16)

__global__ void feat1(const float* __restrict__ x, const float* __restrict__ Wc,
                      const float* __restrict__ Wv, const float* __restrict__ dis,
                      __half* __restrict__ out, int N) {
    __shared__ float xt[16][16];
    int t = threadIdx.x;
    int n0 = blockIdx.x * 16;
    {
        int n = t >> 4, k = t & 15;
        int node = n0 + n;
        xt[n][k] = (node < N) ? x[node * 16 + k] : 0.f;
    }
    const float* wrow = (t < 128) ? (Wc + t * 16) : (Wv + (t - 128) * 16);
    float4 w0 = *(const float4*)(wrow + 0);
    float4 w1 = *(const float4*)(wrow + 4);
    float4 w2 = *(const float4*)(wrow + 8);
    float4 w3 = *(const float4*)(wrow + 12);
    __syncthreads();
    for (int n = 0; n < 16; ++n) {
        int node = n0 + n;
        if (node >= N) break;
        const float* xr = xt[n];
        float s = w0.x * xr[0] + w0.y * xr[1] + w0.z * xr[2] + w0.w * xr[3]
                + w1.x * xr[4] + w1.y * xr[5] + w1.z * xr[6] + w1.w * xr[7]
                + w2.x * xr[8] + w2.y * xr[9] + w2.z * xr[10] + w2.w * xr[11]
                + w3.x * xr[12] + w3.y * xr[13] + w3.z * xr[14] + w3.w * xr[15];
        out[(size_t)node * 256 + t] = __float2half_rn(dis[node] * s);
    }
}

// ---------------- aggregation: h[i] = relu(dis[i]*(self + sum_s t[s]) + b) -------
// t rows are fp16 (512 B); one wave per node; lane l handles 4 feats (uint2)

__global__ void agg(const uint2* __restrict__ tin, const int* __restrict__ rowptr,
                    const int* __restrict__ col, const float* __restrict__ dis,
                    const float* __restrict__ bc, const float* __restrict__ bv,
                    float4* __restrict__ hout, int N) {
    int wid = blockIdx.x * (blockDim.x >> 6) + (threadIdx.x >> 6);
    if (wid >= N) return;
    int lane = threadIdx.x & 63;
    float4 acc = h4_to_f4(tin[(size_t)wid * 64 + lane]);   // self (dis-prescaled)
    int e = rowptr[wid], end = rowptr[wid + 1];
    for (; e + 3 < end; e += 4) {
        int s0 = col[e], s1 = col[e + 1], s2 = col[e + 2], s3 = col[e + 3];
        uint2 m0 = tin[(size_t)s0 * 64 + lane];
        uint2 m1 = tin[(size_t)s1 * 64 + lane];
        uint2 m2 = tin[(size_t)s2 * 64 + lane];
        uint2 m3 = tin[(size_t)s3 * 64 + lane];
        float4 f0 = h4_to_f4(m0), f1 = h4_to_f4(m1);
        float4 f2 = h4_to_f4(m2), f3 = h4_to_f4(m3);
        acc.x += (f0.x + f1.x) + (f2.x + f3.x);
        acc.y += (f0.y + f1.y) + (f2.y + f3.y);
        acc.z += (f0.z + f1.z) + (f2.z + f3.z);
        acc.w += (f0.w + f1.w) + (f2.w + f3.w);
    }
    for (; e < end; ++e) {
        float4 f = h4_to_f4(tin[(size_t)col[e] * 64 + lane]);
        acc.x += f.x; acc.y += f.y; acc.z += f.z; acc.w += f.w;
    }
    float d = dis[wid];
    int f = lane * 4;
    float4 b = (f < 128) ? *(const float4*)(bc + f) : *(const float4*)(bv + f - 128);
    float4 r;
    r.x = fmaxf(fmaf(d, acc.x, b.x), 0.f);
    r.y = fmaxf(fmaf(d, acc.y, b.y), 0.f);
    r.z = fmaxf(fmaf(d, acc.z, b.z), 0.f);
    r.w = fmaxf(fmaf(d, acc.w, b.w), 0.f);
    hout[(size_t)wid * 64 + lane] = r;
}

// ---------------- layer 2 GEMM: t2 = dis * (h @ W^T) -> fp16 ---------------------
// grid (ceil(N/128), 2): y=0 policy (Wtc, h[:,0:128]) -> t[:,0:128]; y=1 value.
// tile 128 nodes x 128 feats, K=128 in 4 phases of 32; thread = 8x8 micro-tile
// (split as node {tn..tn+3, 64+tn..}, feat {tf..tf+3, 64+tf..} for bank-friendly
//  b128 reads). As is [k][n] so A-fragments read as float4.

__global__ __launch_bounds__(256, 4)
void feat2(const float* __restrict__ h, const float* __restrict__ Wtc,
           const float* __restrict__ Wtv, const float* __restrict__ dis,
           __half* __restrict__ tout, int N) {
    __shared__ float As[32][130];
    __shared__ float Bs[32][132];
    int tid = threadIdx.x;
    int n0 = blockIdx.x * 128;
    int br = blockIdx.y;                 // 0 policy, 1 value
    int koff = br * 128;
    const float* Wt = br ? Wtv : Wtc;

    float acc[8][8] = {};

    int sa_k = (tid & 7) * 4;            // 0..28
    int sa_n = tid >> 3;                 // 0..31
    int sb_f = (tid & 31) * 4;           // 0..124
    int sb_k = tid >> 5;                 // 0..7

    int tf = (tid & 15) * 4;
    int tn = (tid >> 4) * 4;

    for (int p = 0; p < 4; ++p) {
        if (p) __syncthreads();
        // stage A slice (k in [32p, 32p+32)), transposed to [k][n]
        for (int it = 0; it < 4; ++it) {
            int n = sa_n + it * 32;
            int node = n0 + n;
            float4 v = make_float4(0.f, 0.f, 0.f, 0.f);
            if (node < N)
                v = *(const float4*)(h + (size_t)node * 256 + koff + p * 32 + sa_k);
            As[sa_k + 0][n] = v.x;
            As[sa_k + 1][n] = v.y;
            As[sa_k + 2][n] = v.z;
            As[sa_k + 3][n] = v.w;
        }
        // stage B slice
        for (int it = 0; it < 4; ++it) {
            int k = sb_k + it * 8;
            *(float4*)(&Bs[k][sb_f]) =
                *(const float4*)(Wt + (size_t)(p * 32 + k) * 128 + sb_f);
        }
        __syncthreads();

#pragma unroll
        for (int k = 0; k < 32; ++k) {
            float4 a0 = *(const float4*)(&As[k][tn]);
            float4 a1 = *(const float4*)(&As[k][64 + tn]);
            float4 b0 = *(const float4*)(&Bs[k][tf]);
            float4 b1 = *(const float4*)(&Bs[k][64 + tf]);
            float ar[8] = {a0.x, a0.y, a0.z, a0.w, a1.x, a1.y, a1.z, a1.w};
            float br_[8] = {b0.x, b0.y, b0.z, b0.w, b1.x, b1.y, b1.z, b1.w};
#pragma unroll
            for (int r = 0; r < 8; ++r)
#pragma unroll
                for (int c = 0; c < 8; ++c)
                    acc[r][c] = fmaf(ar[r], br_[c], acc[r][c]);
        }
    }

    int fo = br * 128;
    for (int hr = 0; hr < 2; ++hr) {
        for (int r = 0; r < 4; ++r) {
            int node = n0 + hr * 64 + tn + r;
            if (node >= N) continue;
            float d = dis[node];
            float* a = acc[hr * 4 + r];
            uint2 p0, p1;
            p0.x = pack_h2(d * a[0], d * a[1]);
            p0.y = pack_h2(d * a[2], d * a[3]);
            p1.x = pack_h2(d * a[4], d * a[5]);
            p1.y = pack_h2(d * a[6], d * a[7]);
            *(uint2*)(tout + (size_t)node * 256 + fo + tf) = p0;
            *(uint2*)(tout + (size_t)node * 256 + fo + 64 + tf) = p1;
        }
    }
}

// ---------------- final 1-wide projections: one wave per node --------------------

__global__ void proj(const float* __restrict__ h, const float* __restrict__ Wp,
                     const float* __restrict__ bp, const float* __restrict__ Wvh,
                     const float* __restrict__ bvh, float* __restrict__ outm,
                     float* __restrict__ outv, int N) {
    int wid = blockIdx.x * (blockDim.x >> 6) + (threadIdx.x >> 6);
    if (wid >= N) return;
    int lane = threadIdx.x & 63;
    const float* hr = h + (size_t)wid * 256;
    float sc = hr[lane] * Wp[lane] + hr[64 + lane] * Wp[64 + lane];
    float sv = hr[128 + lane] * Wvh[lane] + hr[192 + lane] * Wvh[64 + lane];
    for (int off = 32; off; off >>= 1) {
        sc += __shfl_down(sc, off, 64);
        sv += __shfl_down(sv, off, 64);
    }
    if (lane == 0) {
        outm[wid] = sc + bp[0];
        outv[wid] = sv + bvh[0];
    }
}

// ---------------- launch ---------------------------------------------------------

extern "C" void kernel_launch(void* const* d_in, const int* in_sizes, int n_in,
                              void* d_out, int out_size, void* d_ws, size_t ws_size,
                              hipStream_t stream) {
    const float* x   = (const float*)d_in[0];
    const int*   ei  = (const int*)  d_in[1];
    const float* Wc1 = (const float*)d_in[2];
    const float* bc1 = (const float*)d_in[3];
    const float* Wc2 = (const float*)d_in[4];
    const float* bc2 = (const float*)d_in[5];
    const float* Wp  = (const float*)d_in[6];
    const float* bp  = (const float*)d_in[7];
    const float* Wv1 = (const float*)d_in[8];
    const float* bv1 = (const float*)d_in[9];
    const float* Wv2 = (const float*)d_in[10];
    const float* bv2 = (const float*)d_in[11];
    const float* Wvh = (const float*)d_in[12];
    const float* bvh = (const float*)d_in[13];

    const int N = in_sizes[0] / 16;   // 50000
    const int E = in_sizes[1] / 2;    // 800000

    size_t off = 0;
    auto alloc = [&](size_t bytes) -> void* {
        void* p = (char*)d_ws + off;
        off += (bytes + 255) & ~(size_t)255;
        return p;
    };
    int*    cnt    = (int*)alloc((size_t)2 * N * sizeof(int));
    int*    cursor = cnt + N;
    int*    rowptr = (int*)alloc((size_t)(N + 1) * sizeof(int));
    int*    bsum   = (int*)alloc(256 * sizeof(int));
    float*  dis    = (float*)alloc((size_t)N * sizeof(float));
    int*    col    = (int*)alloc((size_t)E * sizeof(int));
    float*  Wtc    = (float*)alloc(128 * 128 * sizeof(float));
    float*  Wtv    = (float*)alloc(128 * 128 * sizeof(float));
    __half* tbuf   = (__half*)alloc((size_t)N * 256 * sizeof(__half)); // 25.6 MB
    float*  hbuf   = (float*)alloc((size_t)N * 256 * sizeof(float));   // 51.2 MB

    float* outm = (float*)d_out;
    float* outv = outm + N;

    const int nbE = (E + TPB - 1) / TPB;
    const int nbN = (N + TPB - 1) / TPB;

    hipMemsetAsync(cnt, 0, (size_t)2 * N * sizeof(int), stream);
    count_deg<<<nbE, TPB, 0, stream>>>(ei, cnt, E);
    scan_a<<<nbN, TPB, 0, stream>>>(cnt, rowptr, dis, bsum, N);
    scan_b<<<1, TPB, 0, stream>>>(bsum, nbN);
    scan_c<<<nbN, TPB, 0, stream>>>(rowptr, bsum, N, E);
    fill_csr<<<nbE, TPB, 0, stream>>>(ei, rowptr, cursor, col, E);
    transpose_w<<<dim3(16, 2), TPB, 0, stream>>>(Wc2, Wtc, Wv2, Wtv);

    // layer 1: x -> tbuf(fp16) -> agg -> hbuf(f32)
    feat1<<<(N + 15) / 16, TPB, 0, stream>>>(x, Wc1, Wv1, dis, tbuf, N);
    agg<<<(N + 3) / 4, TPB, 0, stream>>>((const uint2*)tbuf, rowptr, col, dis,
                                         bc1, bv1, (float4*)hbuf, N);
    // layer 2: hbuf -> tbuf(fp16) -> agg -> hbuf
    feat2<<<dim3((N + 127) / 128, 2), TPB, 0, stream>>>(hbuf, Wtc, Wtv, dis, tbuf, N);
    agg<<<(N + 3) / 4, TPB, 0, stream>>>((const uint2*)tbuf, rowptr, col, dis,
                                         bc2, bv2, (float4*)hbuf, N);
    // heads
    proj<<<(N + 3) / 4, TPB, 0, stream>>>(hbuf, Wp, bp, Wvh, bvh, outm, outv, N);
}

// Round 3
// 332.824 us; speedup vs baseline: 1.4806x; 1.1541x over previous
//
#include <hip/hip_runtime.h>
#include <hip/hip_bf16.h>
#include <hip/hip_fp16.h>

#define TPB 256

typedef _Float16 half8 __attribute__((ext_vector_type(8)));
typedef float f32x4 __attribute__((ext_vector_type(4)));

// ---------------- graph construction ----------------

__global__ void count_deg(const int* __restrict__ ei, int* __restrict__ cnt, int E) {
    int e = blockIdx.x * blockDim.x + threadIdx.x;
    if (e < E) atomicAdd(&cnt[ei[E + e]], 1);
}

__global__ void scan_a(const int* __restrict__ cnt, int* __restrict__ rowptr,
                       float* __restrict__ dis, int* __restrict__ bsum, int N) {
    __shared__ int sd[TPB];
    int t = threadIdx.x;
    int i = blockIdx.x * TPB + t;
    int v = (i < N) ? cnt[i] : 0;
    if (i < N) dis[i] = rsqrtf((float)(v + 1));
    sd[t] = v;
    __syncthreads();
    for (int off = 1; off < TPB; off <<= 1) {
        int x = 0;
        if (t >= off) x = sd[t - off];
        __syncthreads();
        sd[t] += x;
        __syncthreads();
    }
    if (i < N) rowptr[i] = sd[t] - v;               // exclusive
    if (t == TPB - 1) bsum[blockIdx.x] = sd[t];     // inclusive total
}

__global__ void scan_b(int* __restrict__ bsum, int nb) {
    __shared__ int sd[TPB];
    int t = threadIdx.x;
    int v = (t < nb) ? bsum[t] : 0;
    sd[t] = v;
    __syncthreads();
    for (int off = 1; off < TPB; off <<= 1) {
        int x = 0;
        if (t >= off) x = sd[t - off];
        __syncthreads();
        sd[t] += x;
        __syncthreads();
    }
    if (t < nb) bsum[t] = sd[t] - v;                // exclusive block offsets
}

__global__ void scan_c(int* __restrict__ rowptr, const int* __restrict__ bsum,
                       int N, int E) {
    int i = blockIdx.x * TPB + threadIdx.x;
    if (i < N) rowptr[i] += bsum[blockIdx.x];
    if (i == 0) rowptr[N] = E;
}

__global__ void fill_csr(const int* __restrict__ ei, const int* __restrict__ rowptr,
                         int* __restrict__ cursor, int* __restrict__ col, int E) {
    int e = blockIdx.x * blockDim.x + threadIdx.x;
    if (e >= E) return;
    int s = ei[e], d = ei[E + e];
    int pos = rowptr[d] + atomicAdd(&cursor[d], 1);
    col[pos] = s;
}

// ---------------- convert layer-2 weights to fp16 (row-major kept) ---------------

__global__ void convert_w(const float* __restrict__ Wc2, const float* __restrict__ Wv2,
                          __half* __restrict__ Wch, __half* __restrict__ Wvh) {
    int i = blockIdx.x * TPB + threadIdx.x;
    if (i < 128 * 128) {
        Wch[i] = __float2half_rn(Wc2[i]);
        Wvh[i] = __float2half_rn(Wv2[i]);
    }
}

// ---------------- fp16 helpers ---------------------------------------------------

__device__ __forceinline__ float4 h4_to_f4(uint2 m) {
    __half2 h0 = *reinterpret_cast<const __half2*>(&m.x);
    __half2 h1 = *reinterpret_cast<const __half2*>(&m.y);
    float2 f0 = __half22float2(h0);
    float2 f1 = __half22float2(h1);
    return make_float4(f0.x, f0.y, f1.x, f1.y);
}

__device__ __forceinline__ unsigned pack_h2(float a, float b) {
    __half2 h = __floats2half2_rn(a, b);
    return *reinterpret_cast<unsigned*>(&h);
}

// ---------------- layer 1: t[i,0:128]=dis*x@Wc1^T, t[i,128:256]=dis*x@Wv1^T (fp16)

__global__ void feat1(const float* __restrict__ x, const float* __restrict__ Wc,
                      const float* __restrict__ Wv, const float* __restrict__ dis,
                      __half* __restrict__ out, int N) {
    __shared__ float xt[16][16];
    int t = threadIdx.x;
    int n0 = blockIdx.x * 16;
    {
        int n = t >> 4, k = t & 15;
        int node = n0 + n;
        xt[n][k] = (node < N) ? x[node * 16 + k] : 0.f;
    }
    const float* wrow = (t < 128) ? (Wc + t * 16) : (Wv + (t - 128) * 16);
    float4 w0 = *(const float4*)(wrow + 0);
    float4 w1 = *(const float4*)(wrow + 4);
    float4 w2 = *(const float4*)(wrow + 8);
    float4 w3 = *(const float4*)(wrow + 12);
    __syncthreads();
    for (int n = 0; n < 16; ++n) {
        int node = n0 + n;
        if (node >= N) break;
        const float* xr = xt[n];
        float s = w0.x * xr[0] + w0.y * xr[1] + w0.z * xr[2] + w0.w * xr[3]
                + w1.x * xr[4] + w1.y * xr[5] + w1.z * xr[6] + w1.w * xr[7]
                + w2.x * xr[8] + w2.y * xr[9] + w2.z * xr[10] + w2.w * xr[11]
                + w3.x * xr[12] + w3.y * xr[13] + w3.z * xr[14] + w3.w * xr[15];
        out[(size_t)node * 256 + t] = __float2half_rn(dis[node] * s);
    }
}

// ---------------- agg1: h[i] = relu(dis[i]*(self + sum_s t[s]) + b), fp16 out ----
// one wave per node; lane l handles feats 4l..4l+3 (uint2 = 4 fp16)

__global__ void agg1(const uint2* __restrict__ tin, const int* __restrict__ rowptr,
                     const int* __restrict__ col, const float* __restrict__ dis,
                     const float* __restrict__ bc, const float* __restrict__ bv,
                     uint2* __restrict__ hout, int N) {
    int wid = blockIdx.x * (blockDim.x >> 6) + (threadIdx.x >> 6);
    if (wid >= N) return;
    int lane = threadIdx.x & 63;
    float4 acc = h4_to_f4(tin[(size_t)wid * 64 + lane]);   // self (dis-prescaled)
    int e = rowptr[wid], end = rowptr[wid + 1];
    for (; e + 3 < end; e += 4) {
        int s0 = col[e], s1 = col[e + 1], s2 = col[e + 2], s3 = col[e + 3];
        uint2 m0 = tin[(size_t)s0 * 64 + lane];
        uint2 m1 = tin[(size_t)s1 * 64 + lane];
        uint2 m2 = tin[(size_t)s2 * 64 + lane];
        uint2 m3 = tin[(size_t)s3 * 64 + lane];
        float4 f0 = h4_to_f4(m0), f1 = h4_to_f4(m1);
        float4 f2 = h4_to_f4(m2), f3 = h4_to_f4(m3);
        acc.x += (f0.x + f1.x) + (f2.x + f3.x);
        acc.y += (f0.y + f1.y) + (f2.y + f3.y);
        acc.z += (f0.z + f1.z) + (f2.z + f3.z);
        acc.w += (f0.w + f1.w) + (f2.w + f3.w);
    }
    for (; e < end; ++e) {
        float4 f = h4_to_f4(tin[(size_t)col[e] * 64 + lane]);
        acc.x += f.x; acc.y += f.y; acc.z += f.z; acc.w += f.w;
    }
    float d = dis[wid];
    int f = lane * 4;
    float4 b = (f < 128) ? *(const float4*)(bc + f) : *(const float4*)(bv + f - 128);
    uint2 r;
    r.x = pack_h2(fmaxf(fmaf(d, acc.x, b.x), 0.f), fmaxf(fmaf(d, acc.y, b.y), 0.f));
    r.y = pack_h2(fmaxf(fmaf(d, acc.z, b.z), 0.f), fmaxf(fmaf(d, acc.w, b.w), 0.f));
    hout[(size_t)wid * 64 + lane] = r;
}

// ---------------- layer 2 GEMM via MFMA: t2 = dis * (h1 @ W^T), fp16 -------------
// grid (ceil(N/64), 2); block = 4 waves; wave w: nodes [n0+16w, +16), all 128 f.
// No LDS: A/B fragments are 16B-contiguous per lane, loaded straight from global.
// A[m=lane&15][k=quad*8+j]; B[n=lane&15][k=quad*8+j] = W row-major; D col=lane&15,
// row=quad*4+reg (m89/m120-verified layouts).

__global__ __launch_bounds__(256)
void feat2(const __half* __restrict__ h, const __half* __restrict__ Wc,
           const __half* __restrict__ Wv, const float* __restrict__ dis,
           __half* __restrict__ tout, int N) {
    int lane = threadIdx.x & 63;
    int wave = threadIdx.x >> 6;
    int quad = lane >> 4, l16 = lane & 15;
    int n0 = blockIdx.x * 64 + wave * 16;
    int br = blockIdx.y;                       // 0 policy, 1 value
    const _Float16* W = (const _Float16*)(br ? Wv : Wc);
    int koff = br * 128;

    // A fragments for the wave's 16 nodes, K=128 in 4 chunks of 32
    const _Float16* arow = (const _Float16*)h + (size_t)(n0 + l16) * 256 + koff + quad * 8;
    half8 a0 = *(const half8*)(arow + 0);
    half8 a1 = *(const half8*)(arow + 32);
    half8 a2 = *(const half8*)(arow + 64);
    half8 a3 = *(const half8*)(arow + 96);

    f32x4 dv4 = *(const f32x4*)(dis + n0 + quad * 4);   // rows quad*4+r

    _Float16* to = (_Float16*)tout;
#pragma unroll
    for (int j = 0; j < 8; ++j) {
        const _Float16* wrow = W + (size_t)(j * 16 + l16) * 128 + quad * 8;
        half8 b0 = *(const half8*)(wrow + 0);
        half8 b1 = *(const half8*)(wrow + 32);
        half8 b2 = *(const half8*)(wrow + 64);
        half8 b3 = *(const half8*)(wrow + 96);
        f32x4 acc = {0.f, 0.f, 0.f, 0.f};
        acc = __builtin_amdgcn_mfma_f32_16x16x32_f16(a0, b0, acc, 0, 0, 0);
        acc = __builtin_amdgcn_mfma_f32_16x16x32_f16(a1, b1, acc, 0, 0, 0);
        acc = __builtin_amdgcn_mfma_f32_16x16x32_f16(a2, b2, acc, 0, 0, 0);
        acc = __builtin_amdgcn_mfma_f32_16x16x32_f16(a3, b3, acc, 0, 0, 0);
        int fo = koff + j * 16 + l16;          // D col
#pragma unroll
        for (int r = 0; r < 4; ++r) {
            int node = n0 + quad * 4 + r;      // D row
            if (node < N)
                to[(size_t)node * 256 + fo] = (_Float16)(dv4[r] * acc[r]);
        }
    }
}

// ---------------- agg2 + proj fused: per node, aggregate then head dots ----------
// lane l holds feats 4l..4l+3 of h2; policy = lanes 0..31, value = lanes 32..63

__global__ void agg2(const uint2* __restrict__ tin, const int* __restrict__ rowptr,
                     const int* __restrict__ col, const float* __restrict__ dis,
                     const float* __restrict__ bc, const float* __restrict__ bv,
                     const float* __restrict__ Wp, const float* __restrict__ bp,
                     const float* __restrict__ Wvh, const float* __restrict__ bvh,
                     float* __restrict__ outm, float* __restrict__ outv, int N) {
    int wid = blockIdx.x * (blockDim.x >> 6) + (threadIdx.x >> 6);
    if (wid >= N) return;
    int lane = threadIdx.x & 63;
    float4 acc = h4_to_f4(tin[(size_t)wid * 64 + lane]);   // self
    int e = rowptr[wid], end = rowptr[wid + 1];
    for (; e + 3 < end; e += 4) {
        int s0 = col[e], s1 = col[e + 1], s2 = col[e + 2], s3 = col[e + 3];
        uint2 m0 = tin[(size_t)s0 * 64 + lane];
        uint2 m1 = tin[(size_t)s1 * 64 + lane];
        uint2 m2 = tin[(size_t)s2 * 64 + lane];
        uint2 m3 = tin[(size_t)s3 * 64 + lane];
        float4 f0 = h4_to_f4(m0), f1 = h4_to_f4(m1);
        float4 f2 = h4_to_f4(m2), f3 = h4_to_f4(m3);
        acc.x += (f0.x + f1.x) + (f2.x + f3.x);
        acc.y += (f0.y + f1.y) + (f2.y + f3.y);
        acc.z += (f0.z + f1.z) + (f2.z + f3.z);
        acc.w += (f0.w + f1.w) + (f2.w + f3.w);
    }
    for (; e < end; ++e) {
        float4 f = h4_to_f4(tin[(size_t)col[e] * 64 + lane]);
        acc.x += f.x; acc.y += f.y; acc.z += f.z; acc.w += f.w;
    }
    float d = dis[wid];
    int f = lane * 4;
    float4 b = (f < 128) ? *(const float4*)(bc + f) : *(const float4*)(bv + f - 128);
    float4 h2;
    h2.x = fmaxf(fmaf(d, acc.x, b.x), 0.f);
    h2.y = fmaxf(fmaf(d, acc.y, b.y), 0.f);
    h2.z = fmaxf(fmaf(d, acc.z, b.z), 0.f);
    h2.w = fmaxf(fmaf(d, acc.w, b.w), 0.f);
    // head dot: policy weights for lanes 0..31, value weights for lanes 32..63
    const float* wptr = (lane < 32) ? (Wp + lane * 4) : (Wvh + (lane - 32) * 4);
    float4 w = *(const float4*)wptr;
    float p = h2.x * w.x + h2.y * w.y + h2.z * w.z + h2.w * w.w;
    for (int off = 16; off; off >>= 1) p += __shfl_down(p, off, 32);
    if (lane == 0)  outm[wid] = p + bp[0];
    if (lane == 32) outv[wid] = p + bvh[0];
}

// ---------------- launch ---------------------------------------------------------

extern "C" void kernel_launch(void* const* d_in, const int* in_sizes, int n_in,
                              void* d_out, int out_size, void* d_ws, size_t ws_size,
                              hipStream_t stream) {
    const float* x   = (const float*)d_in[0];
    const int*   ei  = (const int*)  d_in[1];
    const float* Wc1 = (const float*)d_in[2];
    const float* bc1 = (const float*)d_in[3];
    const float* Wc2 = (const float*)d_in[4];
    const float* bc2 = (const float*)d_in[5];
    const float* Wp  = (const float*)d_in[6];
    const float* bp  = (const float*)d_in[7];
    const float* Wv1 = (const float*)d_in[8];
    const float* bv1 = (const float*)d_in[9];
    const float* Wv2 = (const float*)d_in[10];
    const float* bv2 = (const float*)d_in[11];
    const float* Wvh = (const float*)d_in[12];
    const float* bvh = (const float*)d_in[13];

    const int N = in_sizes[0] / 16;   // 50000
    const int E = in_sizes[1] / 2;    // 800000
    const int Npad = (N + 63) & ~63;  // pad so MFMA tail tiles read in-bounds

    size_t off = 0;
    auto alloc = [&](size_t bytes) -> void* {
        void* p = (char*)d_ws + off;
        off += (bytes + 255) & ~(size_t)255;
        return p;
    };
    int*    cnt    = (int*)alloc((size_t)2 * N * sizeof(int));
    int*    cursor = cnt + N;
    int*    rowptr = (int*)alloc((size_t)(N + 1) * sizeof(int));
    int*    bsum   = (int*)alloc(256 * sizeof(int));
    float*  dis    = (float*)alloc((size_t)Npad * sizeof(float));
    int*    col    = (int*)alloc((size_t)E * sizeof(int));
    __half* Wch    = (__half*)alloc(128 * 128 * sizeof(__half));
    __half* Wvh2   = (__half*)alloc(128 * 128 * sizeof(__half));
    __half* tbuf   = (__half*)alloc((size_t)Npad * 256 * sizeof(__half)); // 25.6 MB
    __half* hbuf   = (__half*)alloc((size_t)Npad * 256 * sizeof(__half)); // 25.6 MB

    float* outm = (float*)d_out;
    float* outv = outm + N;

    const int nbE = (E + TPB - 1) / TPB;
    const int nbN = (N + TPB - 1) / TPB;

    hipMemsetAsync(cnt, 0, (size_t)2 * N * sizeof(int), stream);
    count_deg<<<nbE, TPB, 0, stream>>>(ei, cnt, E);
    scan_a<<<nbN, TPB, 0, stream>>>(cnt, rowptr, dis, bsum, N);
    scan_b<<<1, TPB, 0, stream>>>(bsum, nbN);
    scan_c<<<nbN, TPB, 0, stream>>>(rowptr, bsum, N, E);
    fill_csr<<<nbE, TPB, 0, stream>>>(ei, rowptr, cursor, col, E);
    convert_w<<<64, TPB, 0, stream>>>(Wc2, Wv2, Wch, Wvh2);

    // layer 1: x -> tbuf(fp16) -> agg1 -> hbuf(fp16)
    feat1<<<(N + 15) / 16, TPB, 0, stream>>>(x, Wc1, Wv1, dis, tbuf, N);
    agg1<<<(N + 3) / 4, TPB, 0, stream>>>((const uint2*)tbuf, rowptr, col, dis,
                                          bc1, bv1, (uint2*)hbuf, N);
    // layer 2: hbuf -> (MFMA) -> tbuf(fp16) -> agg2(+proj) -> out
    feat2<<<dim3((N + 63) / 64, 2), TPB, 0, stream>>>(hbuf, Wch, Wvh2, dis, tbuf, N);
    agg2<<<(N + 3) / 4, TPB, 0, stream>>>((const uint2*)tbuf, rowptr, col, dis,
                                          bc2, bv2, Wp, bp, Wvh, bvh,
                                          outm, outv, N);
}